// Round 7
// baseline (669.218 us; speedup 1.0000x reference)
//
#include <hip/hip_runtime.h>
#include <math.h>

#define NB_B 512
#define NE 100000
#define NE_PAD 100032   // padded to multiple of 64 (zero rows 100000..100031)
#define DD 200
#define CC 32
#define FCIN 10368   // 32*18*18
#define HW 324       // 18*18
#define BNEPS 1e-5f
#define KP 224       // scores K padded to multiple of 32 for MFMA

#define ENT_BLKS 10941   // 100032*28/256 exactly
#define FCW_BLKS 1013
#define GATH_OFF (ENT_BLKS + FCW_BLKS)   // 11954

typedef __attribute__((ext_vector_type(8))) short short8;   // 8 bf16 = 4 VGPRs
typedef __attribute__((ext_vector_type(4))) float floatx4;  // MFMA acc

// dacc (double) slots:
// 0: bn0 sum, 1: bn0 sumsq (also l2 for h_e+r_e)
// 2..33: bn1 per-channel sum, 34..65: bn1 per-channel sumsq
// 67: fc_w sumsq, 68: softplus sum, 69: scores sum, 70: pos-scores sum

static __device__ __forceinline__ float blk_reduce(float v, volatile float* sbuf) {
  for (int o = 32; o > 0; o >>= 1) v += __shfl_down(v, o, 64);
  int lane = threadIdx.x & 63, wid = threadIdx.x >> 6;
  if (lane == 0) sbuf[wid] = v;
  __syncthreads();
  float r = 0.f;
  int nw = (blockDim.x + 63) >> 6;
  if ((int)threadIdx.x < nw) r = sbuf[threadIdx.x];
  if (threadIdx.x < 64) {
    for (int o = 32; o > 0; o >>= 1) r += __shfl_down(r, o, 64);
  }
  __syncthreads();
  return r;  // valid on thread 0
}

static __device__ __forceinline__ unsigned short f32_to_bf16(float f) {
  unsigned int u = __float_as_uint(f);
  u += 0x7fffu + ((u >> 16) & 1u);  // round-to-nearest-even
  return (unsigned short)(u >> 16);
}
static __device__ __forceinline__ float bf16_to_f32(unsigned short b) {
  return __uint_as_float(((unsigned int)b) << 16);
}

// K1: fused prep. Blocks [0,ENT_BLKS): entity_w f32 -> bf16, rows padded to NE_PAD
// (zero rows >= NE), cols padded 200->224. Blocks [ENT_BLKS,GATH_OFF): fc_w -> bf16
// + sumsq. Blocks [GATH_OFF, +512): gather h/r -> x0, bn0 stats.
__global__ __launch_bounds__(256) void k_cvt(const float* __restrict__ ent,
                                             unsigned short* __restrict__ entb,
                                             const float* __restrict__ fcw,
                                             unsigned short* __restrict__ fcwb,
                                             const float* __restrict__ rel,
                                             const int* __restrict__ h,
                                             const int* __restrict__ r,
                                             float* __restrict__ x0,
                                             double* dacc) {
  if (blockIdx.x < ENT_BLKS) {
    int g = blockIdx.x * 256 + threadIdx.x;   // 0 .. 2,800,895  (100032*28)
    int row = g / 28;
    int c8 = (g - row * 28) * 8;
    ushort4 o0, o1;
    if (c8 < 200 && row < NE) {
      const float4* s = (const float4*)(ent + (long)row * DD + c8);
      float4 u = s[0], v = s[1];
      o0.x = f32_to_bf16(u.x); o0.y = f32_to_bf16(u.y);
      o0.z = f32_to_bf16(u.z); o0.w = f32_to_bf16(u.w);
      o1.x = f32_to_bf16(v.x); o1.y = f32_to_bf16(v.y);
      o1.z = f32_to_bf16(v.z); o1.w = f32_to_bf16(v.w);
    } else {
      o0.x = o0.y = o0.z = o0.w = 0;
      o1.x = o1.y = o1.z = o1.w = 0;
    }
    ushort4* d = (ushort4*)(entb + (long)row * KP + c8);
    d[0] = o0; d[1] = o1;
  } else if (blockIdx.x < GATH_OFF) {
    int g = (blockIdx.x - ENT_BLKS) * 256 + threadIdx.x;   // x8 elems; 2,073,600 total
    float sq = 0.f;
    if (g < 259200) {
      const float4* s = (const float4*)(fcw + (long)g * 8);
      float4 u = s[0], v = s[1];
      sq = u.x*u.x + u.y*u.y + u.z*u.z + u.w*u.w
         + v.x*v.x + v.y*v.y + v.z*v.z + v.w*v.w;
      ushort4 o0, o1;
      o0.x = f32_to_bf16(u.x); o0.y = f32_to_bf16(u.y);
      o0.z = f32_to_bf16(u.z); o0.w = f32_to_bf16(u.w);
      o1.x = f32_to_bf16(v.x); o1.y = f32_to_bf16(v.y);
      o1.z = f32_to_bf16(v.z); o1.w = f32_to_bf16(v.w);
      ushort4* d = (ushort4*)(fcwb + (long)g * 8);
      d[0] = o0; d[1] = o1;
    }
    __shared__ float sbuf[8];
    float tq = blk_reduce(sq, sbuf);
    if (threadIdx.x == 0) atomicAdd(&dacc[67], (double)tq);
  } else {
    int b = blockIdx.x - GATH_OFF;
    int hi = h[b], ri = r[b];
    float s = 0.f, sq = 0.f;
    for (int i = threadIdx.x; i < 400; i += 256) {
      float v = (i < 200) ? ent[(long)hi * DD + i] : rel[(long)ri * DD + (i - 200)];
      x0[b * 400 + i] = v;
      s += v; sq += v * v;
    }
    __shared__ float sbuf[8];
    float ts = blk_reduce(s, sbuf);
    float tq = blk_reduce(sq, sbuf);
    if (threadIdx.x == 0) {
      atomicAdd(&dacc[0], (double)ts);
      atomicAdd(&dacc[1], (double)tq);
    }
  }
}

// K2: bn0 + conv3x3 + conv_b -> yb bf16 [512 x 10368] (pre-bn1); bn1 stats (f32)
__global__ __launch_bounds__(256) void k_conv(const float* __restrict__ x0,
                       const float* __restrict__ convw, const float* __restrict__ convb,
                       const float* __restrict__ g0, const float* __restrict__ b0,
                       unsigned short* __restrict__ yb, double* dacc) {
  __shared__ float xs[400], wsm[288], cbs[32], ssum[32], ssq[32];
  __shared__ float a0s, s0s;
  int b = blockIdx.x, t = threadIdx.x;
  for (int i = t; i < 400; i += 256) xs[i] = x0[b * 400 + i];
  for (int i = t; i < 288; i += 256) wsm[i] = convw[i];
  if (t < 32) cbs[t] = convb[t];
  if (t == 0) {
    double m = dacc[0] / 204800.0;
    double v = dacc[1] / 204800.0 - m * m;
    float a = g0[0] * rsqrtf((float)v + BNEPS);
    a0s = a; s0s = b0[0] - (float)m * a;
  }
  __syncthreads();
  float a0 = a0s, s0 = s0s;
  for (int i = t; i < 400; i += 256) xs[i] = a0 * xs[i] + s0;
  __syncthreads();
  int c = t >> 3, sub = t & 7;
  const float* w = &wsm[c * 9];
  float cb = cbs[c];
  float s = 0.f, sq = 0.f;
  for (int e = sub; e < HW; e += 8) {
    int oh = e / 18, ow = e - oh * 18;
    const float* xp = &xs[oh * 20 + ow];
    float acc = cb
       + xp[0] * w[0] + xp[1] * w[1] + xp[2] * w[2]
       + xp[20] * w[3] + xp[21] * w[4] + xp[22] * w[5]
       + xp[40] * w[6] + xp[41] * w[7] + xp[42] * w[8];
    yb[(long)b * FCIN + c * HW + e] = f32_to_bf16(acc);
    s += acc; sq += acc * acc;
  }
  s += __shfl_xor(s, 1, 64); sq += __shfl_xor(sq, 1, 64);
  s += __shfl_xor(s, 2, 64); sq += __shfl_xor(sq, 2, 64);
  s += __shfl_xor(s, 4, 64); sq += __shfl_xor(sq, 4, 64);
  if (sub == 0) { ssum[c] = s; ssq[c] = sq; }
  __syncthreads();
  if (t < 32) {
    atomicAdd(&dacc[2 + t], (double)ssum[t]);
    atomicAdd(&dacc[34 + t], (double)ssq[t]);
  }
}

// K3: in-place bn1 + relu on yb (bf16); a1/sh1 computed per-block from dacc
__global__ __launch_bounds__(256) void k_prep(unsigned short* __restrict__ yb,
                                              const float* __restrict__ g1,
                                              const float* __restrict__ b1,
                                              const double* __restrict__ dacc) {
  __shared__ float a1s[32], sh1s[32];
  int t = threadIdx.x;
  if (t < 32) {
    double cnt = 512.0 * 324.0;
    double m = dacc[2 + t] / cnt, v = dacc[34 + t] / cnt - m * m;
    float a = g1[t] * rsqrtf((float)v + BNEPS);
    a1s[t] = a; sh1s[t] = b1[t] - (float)m * a;
  }
  __syncthreads();
  int g = blockIdx.x * 256 + t;          // 0..663551 (x8 elems)
  int row = g / 1296;
  int c8 = (g - row * 1296) * 8;
  unsigned short* p = yb + (long)row * FCIN + c8;
  ushort4 v0 = ((ushort4*)p)[0], v1 = ((ushort4*)p)[1];
  unsigned short e[8] = {v0.x, v0.y, v0.z, v0.w, v1.x, v1.y, v1.z, v1.w};
#pragma unroll
  for (int j = 0; j < 8; j++) {
    int c = (c8 + j) / HW;
    float f = a1s[c] * bf16_to_f32(e[j]) + sh1s[c];
    e[j] = f32_to_bf16(fmaxf(f, 0.f));
  }
  v0.x = e[0]; v0.y = e[1]; v0.z = e[2]; v0.w = e[3];
  v1.x = e[4]; v1.y = e[5]; v1.z = e[6]; v1.w = e[7];
  ((ushort4*)p)[0] = v0; ((ushort4*)p)[1] = v1;
}

// K4: FC GEMM via bf16 MFMA. 256 blocks = 8 kslices x (8 mt x 4 nt). Per block
// 4 waves; global k-wave q = ks*4+wv handles chunks c = q + 32*j (324 chunks of 32).
// LDS cross-wave reduce, then atomicAdd into Cfc (8 contenders/address).
__global__ __launch_bounds__(256, 2) void k_fc2(const unsigned short* __restrict__ yb,
                                                const unsigned short* __restrict__ fcwb,
                                                float* __restrict__ Cfc) {
  __shared__ float red[4][64][64];  // 64 KB
  int bid = blockIdx.x;
  int ks = bid >> 5;                // 0..7
  int rem = bid & 31;
  int mt = rem >> 2, nt = rem & 3;
  int m0 = mt * 64, n0 = nt * 64;
  int t = threadIdx.x, wv = t >> 6, lane = t & 63;
  int quad = lane >> 4, lr = lane & 15;
  int q = ks * 4 + wv;              // 0..31
  int nch = (q < 4) ? 11 : 10;      // chunks c = q + 32*j < 324

  const unsigned short* arow[4];
  const unsigned short* brow[4];
#pragma unroll
  for (int mi = 0; mi < 4; mi++)
    arow[mi] = yb + (long)(m0 + mi * 16 + lr) * FCIN + (long)q * 32 + quad * 8;
#pragma unroll
  for (int ni = 0; ni < 4; ni++) {
    int d = n0 + ni * 16 + lr;
    if (d > DD - 1) d = DD - 1;
    brow[ni] = fcwb + (long)d * FCIN + (long)q * 32 + quad * 8;
  }

  floatx4 acc[4][4];
#pragma unroll
  for (int i = 0; i < 4; i++)
#pragma unroll
    for (int j = 0; j < 4; j++) acc[i][j] = (floatx4){0.f, 0.f, 0.f, 0.f};

  short8 sA[2][4], sB[2][4];
#pragma unroll
  for (int c = 0; c < 2; c++) {
#pragma unroll
    for (int mi = 0; mi < 4; mi++) sA[c][mi] = *(const short8*)(arow[mi] + c * 1024);
#pragma unroll
    for (int ni = 0; ni < 4; ni++) sB[c][ni] = *(const short8*)(brow[ni] + c * 1024);
  }
  for (int j = 0; j < nch; j++) {
    int s = j & 1;
#pragma unroll
    for (int ni = 0; ni < 4; ni++)
#pragma unroll
      for (int mi = 0; mi < 4; mi++)
        acc[mi][ni] = __builtin_amdgcn_mfma_f32_16x16x32_bf16(sA[s][mi], sB[s][ni], acc[mi][ni], 0, 0, 0);
    if (j + 2 < nch) {
#pragma unroll
      for (int mi = 0; mi < 4; mi++) sA[s][mi] = *(const short8*)(arow[mi] + (j + 2) * 1024);
#pragma unroll
      for (int ni = 0; ni < 4; ni++) sB[s][ni] = *(const short8*)(brow[ni] + (j + 2) * 1024);
    }
  }

#pragma unroll
  for (int mi = 0; mi < 4; mi++)
#pragma unroll
    for (int ni = 0; ni < 4; ni++)
#pragma unroll
      for (int rg = 0; rg < 4; rg++)
        red[wv][mi * 16 + quad * 4 + rg][ni * 16 + lr] = acc[mi][ni][rg];
  __syncthreads();
#pragma unroll
  for (int i = 0; i < 16; i++) {
    int o = t + 256 * i;
    int row = o >> 6, col = o & 63;
    if (n0 + col < DD) {
      float v = red[0][row][col] + red[1][row][col] + red[2][row][col] + red[3][row][col];
      atomicAdd(&Cfc[(m0 + row) * DD + n0 + col], v);
    }
  }
}

// K5: bn2 stats per feature -> a2/b2c
__global__ void k_bn2stats(const float* __restrict__ Cfc, const float* __restrict__ fcb,
                           const float* __restrict__ g2, const float* __restrict__ b2,
                           float* __restrict__ a2, float* __restrict__ b2c) {
  int d = blockIdx.x, lane = threadIdx.x;  // 64 threads
  float s = 0.f, sq = 0.f;
  for (int b = lane; b < NB_B; b += 64) {
    float v = Cfc[b * DD + d] + fcb[d];
    s += v; sq += v * v;
  }
  for (int o = 32; o > 0; o >>= 1) { s += __shfl_down(s, o, 64); sq += __shfl_down(sq, o, 64); }
  if (lane == 0) {
    float m = s / 512.f, v = sq / 512.f - m * m;
    float a = g2[d] * rsqrtf(v + BNEPS);
    a2[d] = a; b2c[d] = b2[d] - m * a;
  }
}

// K6: x_final row: leaky_relu(bn2(fc)) -> xf f32 + xfb bf16(padded); fused pos-score
__global__ __launch_bounds__(256) void k_xfinal(const float* __restrict__ Cfc,
                         const float* __restrict__ fcb,
                         const float* __restrict__ a2, const float* __restrict__ b2c,
                         const float* __restrict__ ent, const float* __restrict__ bias,
                         const int* __restrict__ pos,
                         float* __restrict__ xf, unsigned short* __restrict__ xfb,
                         double* dacc) {
  __shared__ float xs[224];
  __shared__ float sbuf[8];
  int b = blockIdx.x, t = threadIdx.x;
  if (t < KP) {
    float xv = 0.f;
    if (t < DD) {
      float v = Cfc[b * DD + t] + fcb[t];
      xv = a2[t] * v + b2c[t];
      xv = xv >= 0.f ? xv : 0.01f * xv;
      xf[b * DD + t] = xv;
    }
    xfb[b * KP + t] = f32_to_bf16(xv);
    xs[t] = xv;
  }
  __syncthreads();
  int e = pos[b];
  float s = (t < DD) ? xs[t] * ent[(long)e * DD + t] : 0.f;
  float ts = blk_reduce(s, sbuf);
  if (t == 0) atomicAdd(&dacc[70], (double)(ts + bias[e]));
}

// K7: scores GEMM + fused softplus loss. 512 thr = 8 waves x 64 batch rows = all 512
// rows per block (entb read ONCE grid-wide). 521 blocks x exactly 3 contiguous tiles.
// af register-resident (amdgpu_waves_per_eu(2,2) pins the allocator); cross-tile
// rolling B prefetch so the epilogue hides next-tile load latency.
__global__ __attribute__((amdgpu_flat_work_group_size(512, 512), amdgpu_waves_per_eu(2, 2)))
void k_scores3(const unsigned short* __restrict__ entb,  // [NE_PAD(+64)][KP] bf16
               const unsigned short* __restrict__ xfb,   // [512][KP] bf16
               const float* __restrict__ bias, double* dacc) {
  __shared__ float sbuf[8];
  int t = threadIdx.x;
  int wv = t >> 6, lane = t & 63;
  int quad = lane >> 4, lr = lane & 15;

  // A fragments: 64 batch rows per wave, resident for whole kernel (112 VGPR)
  short8 af[4][7];
#pragma unroll
  for (int mi = 0; mi < 4; mi++) {
    const unsigned short* ap = xfb + (size_t)(wv * 64 + mi * 16 + lr) * KP + quad * 8;
#pragma unroll
    for (int kc = 0; kc < 7; kc++) af[mi][kc] = *(const short8*)(ap + kc * 32);
  }

  int t0 = blockIdx.x * 3;
  const unsigned short* bp[4];
#pragma unroll
  for (int ni = 0; ni < 4; ni++)
    bp[ni] = entb + (size_t)(t0 * 64 + ni * 16 + lr) * KP + quad * 8;

  float sp = 0.f, ss = 0.f;
  short8 bs[2][4];
#pragma unroll
  for (int ni = 0; ni < 4; ni++) bs[0][ni] = *(const short8*)(bp[ni]);
#pragma unroll
  for (int ni = 0; ni < 4; ni++) bs[1][ni] = *(const short8*)(bp[ni] + 32);

#pragma unroll
  for (int tile = 0; tile < 3; tile++) {
    int e0 = (t0 + tile) * 64;
    float b4[4], g4[4];
#pragma unroll
    for (int ni = 0; ni < 4; ni++) {
      int e = e0 + ni * 16 + lr;
      int ec = e < NE ? e : (NE - 1);
      b4[ni] = bias[ec];
      g4[ni] = (e < NE) ? 1.f : 0.f;
    }
    const unsigned short* bpn[4];
#pragma unroll
    for (int ni = 0; ni < 4; ni++) bpn[ni] = bp[ni] + 64 * KP;

    floatx4 acc[4][4];
#pragma unroll
    for (int i = 0; i < 4; i++)
#pragma unroll
      for (int j = 0; j < 4; j++) acc[i][j] = (floatx4){0.f, 0.f, 0.f, 0.f};

#pragma unroll
    for (int kc = 0; kc < 7; kc++) {
      int s = kc & 1;
#pragma unroll
      for (int ni = 0; ni < 4; ni++)
#pragma unroll
        for (int mi = 0; mi < 4; mi++)
          acc[mi][ni] = __builtin_amdgcn_mfma_f32_16x16x32_bf16(af[mi][kc], bs[s][ni], acc[mi][ni], 0, 0, 0);
      if (kc < 5) {
        // prefetch this tile's chunk kc+2 into the just-freed buffer
#pragma unroll
        for (int ni = 0; ni < 4; ni++) bs[s][ni] = *(const short8*)(bp[ni] + (kc + 2) * 32);
      } else {
        // rolling prefetch of NEXT tile: kc=5 -> chunk1 (used at next kc=1),
        // kc=6 -> chunk0 (used at next kc=0); epilogue below hides the latency.
        int nc = (kc == 5) ? 1 : 0;
#pragma unroll
        for (int ni = 0; ni < 4; ni++) bs[s][ni] = *(const short8*)(bpn[ni] + nc * 32);
      }
    }

    // epilogue: row(batch) = wv*64 + mi*16 + quad*4 + rg, col(entity) = e0 + ni*16 + lr
#pragma unroll
    for (int ni = 0; ni < 4; ni++) {
      float gl = g4[ni] * 0.6931471805599453f;  // gate * ln2
#pragma unroll
      for (int mi = 0; mi < 4; mi++) {
#pragma unroll
        for (int rg = 0; rg < 4; rg++) {
          float s1 = acc[mi][ni][rg] + b4[ni];
          float m = fmaxf(s1, 0.f);
          float ex = __builtin_amdgcn_exp2f(__builtin_fabsf(s1) * -1.4426950408889634f);
          float lg = __builtin_amdgcn_logf(1.f + ex);  // log2(1+ex)
          sp = fmaf(g4[ni], m, sp);
          sp = fmaf(gl, lg, sp);
          ss = fmaf(g4[ni], s1, ss);
        }
      }
    }
#pragma unroll
    for (int ni = 0; ni < 4; ni++) bp[ni] = bpn[ni];
  }

  float tsp = blk_reduce(sp, sbuf);
  float tss = blk_reduce(ss, sbuf);
  if (t == 0) {
    atomicAdd(&dacc[68], (double)tsp);
    atomicAdd(&dacc[69], (double)tss);
  }
}

// K8: final scalar (64 threads; also does conv_w L2 reduce)
__global__ void k_final(const float* __restrict__ convw, const double* dacc, float* out) {
  int t = threadIdx.x;
  float sq = 0.f;
  for (int i = t; i < 288; i += 64) { float w = convw[i]; sq += w * w; }
  for (int o = 32; o > 0; o >>= 1) sq += __shfl_down(sq, o, 64);
  if (t == 0) {
    double SP = dacc[68], S2 = dacc[69], S3 = dacc[70];
    double xy = S2 / (double)NE + 0.9 * S3;
    double kg = (SP - xy) / ((double)NB_B * (double)NE);
    double l2 = dacc[1] / 204800.0 + (double)sq / 576.0 + dacc[67] / 400.0;
    out[0] = (float)(kg + 1e-5 * l2);
  }
}

extern "C" void kernel_launch(void* const* d_in, const int* in_sizes, int n_in,
                              void* d_out, int out_size, void* d_ws, size_t ws_size,
                              hipStream_t stream) {
  const float* ent   = (const float*)d_in[0];
  const float* rel   = (const float*)d_in[1];
  const float* convw = (const float*)d_in[2];
  const float* convb = (const float*)d_in[3];
  const float* fcw   = (const float*)d_in[4];
  const float* fcb   = (const float*)d_in[5];
  const float* bias  = (const float*)d_in[6];
  const float* g0    = (const float*)d_in[7];
  const float* b0    = (const float*)d_in[8];
  const float* g1    = (const float*)d_in[9];
  const float* b1    = (const float*)d_in[10];
  const float* g2    = (const float*)d_in[11];
  const float* b2    = (const float*)d_in[12];
  const int*   h     = (const int*)d_in[13];
  const int*   r     = (const int*)d_in[14];
  const int*   pos   = (const int*)d_in[15];

  char* ws = (char*)d_ws;
  double* dacc = (double*)(ws + 0);                        // 8 KB
  float* a2  = (float*)(ws + 16384 + 256);                 // 200
  float* b2c = (float*)(ws + 16384 + 1056);                // 200
  float* x0  = (float*)(ws + 32768);                       // 512*400 f32      (819200 B)
  float* Cfc = (float*)(ws + 851968);                      // 512*200 f32      (409600 B)
  float* xf  = (float*)(ws + 1261568);                     // 512*200 f32      (409600 B)
  unsigned short* yb   = (unsigned short*)(ws + 1671168);  // 512*10368 bf16   (10616832 B)
  unsigned short* fcwb = (unsigned short*)(ws + 12288000); // 200*10368 bf16   (4147200 B)
  unsigned short* xfb  = (unsigned short*)(ws + 16435200); // 512*224 bf16     (229376 B)
  unsigned short* entb = (unsigned short*)(ws + 16664576); // (100032+64)*224 bf16

  hipMemsetAsync(dacc, 0, 8192, stream);
  hipMemsetAsync(Cfc, 0, 409600, stream);

  k_cvt<<<GATH_OFF + 512, 256, 0, stream>>>(ent, entb, fcw, fcwb, rel, h, r, x0, dacc);
  k_conv<<<512, 256, 0, stream>>>(x0, convw, convb, g0, b0, yb, dacc);
  k_prep<<<2592, 256, 0, stream>>>(yb, g1, b1, dacc);
  k_fc2<<<256, 256, 0, stream>>>(yb, fcwb, Cfc);
  k_bn2stats<<<200, 64, 0, stream>>>(Cfc, fcb, g2, b2, a2, b2c);
  k_xfinal<<<512, 256, 0, stream>>>(Cfc, fcb, a2, b2c, ent, bias, pos, xf, xfb, dacc);
  k_scores3<<<521, 512, 0, stream>>>(entb, xfb, bias, dacc);
  k_final<<<1, 64, 0, stream>>>(convw, dacc, (float*)d_out);
}

// Round 8
// 371.796 us; speedup vs baseline: 1.8000x; 1.8000x over previous
//
#include <hip/hip_runtime.h>
#include <math.h>

#define NB_B 512
#define NE 100000
#define NE_PAD 100032   // padded to multiple of 64 (zero rows 100000..100031)
#define DD 200
#define CC 32
#define FCIN 10368   // 32*18*18
#define HW 324       // 18*18
#define BNEPS 1e-5f
#define KP 224       // scores K padded to multiple of 32 for MFMA

#define ENT_BLKS 10941   // 100032*28/256 exactly
#define FCW_BLKS 1013
#define GATH_OFF (ENT_BLKS + FCW_BLKS)   // 11954

typedef __attribute__((ext_vector_type(8))) short short8;   // 8 bf16 = 4 VGPRs
typedef __attribute__((ext_vector_type(4))) float floatx4;  // MFMA acc

// dacc (double) slots:
// 0: bn0 sum, 1: bn0 sumsq (also l2 for h_e+r_e)
// 2..33: bn1 per-channel sum, 34..65: bn1 per-channel sumsq
// 67: fc_w sumsq, 68: softplus sum, 69: scores sum, 70: pos-scores sum

static __device__ __forceinline__ float blk_reduce(float v, volatile float* sbuf) {
  for (int o = 32; o > 0; o >>= 1) v += __shfl_down(v, o, 64);
  int lane = threadIdx.x & 63, wid = threadIdx.x >> 6;
  if (lane == 0) sbuf[wid] = v;
  __syncthreads();
  float r = 0.f;
  int nw = (blockDim.x + 63) >> 6;
  if ((int)threadIdx.x < nw) r = sbuf[threadIdx.x];
  if (threadIdx.x < 64) {
    for (int o = 32; o > 0; o >>= 1) r += __shfl_down(r, o, 64);
  }
  __syncthreads();
  return r;  // valid on thread 0
}

static __device__ __forceinline__ unsigned short f32_to_bf16(float f) {
  unsigned int u = __float_as_uint(f);
  u += 0x7fffu + ((u >> 16) & 1u);  // round-to-nearest-even
  return (unsigned short)(u >> 16);
}
static __device__ __forceinline__ float bf16_to_f32(unsigned short b) {
  return __uint_as_float(((unsigned int)b) << 16);
}

// K1: fused prep. Blocks [0,ENT_BLKS): entity_w f32 -> bf16, rows padded to NE_PAD
// (zero rows >= NE), cols padded 200->224. Blocks [ENT_BLKS,GATH_OFF): fc_w -> bf16
// + sumsq. Blocks [GATH_OFF, +512): gather h/r -> x0, bn0 stats.
__global__ __launch_bounds__(256) void k_cvt(const float* __restrict__ ent,
                                             unsigned short* __restrict__ entb,
                                             const float* __restrict__ fcw,
                                             unsigned short* __restrict__ fcwb,
                                             const float* __restrict__ rel,
                                             const int* __restrict__ h,
                                             const int* __restrict__ r,
                                             float* __restrict__ x0,
                                             double* dacc) {
  if (blockIdx.x < ENT_BLKS) {
    int g = blockIdx.x * 256 + threadIdx.x;   // 0 .. 2,800,895  (100032*28)
    int row = g / 28;
    int c8 = (g - row * 28) * 8;
    ushort4 o0, o1;
    if (c8 < 200 && row < NE) {
      const float4* s = (const float4*)(ent + (long)row * DD + c8);
      float4 u = s[0], v = s[1];
      o0.x = f32_to_bf16(u.x); o0.y = f32_to_bf16(u.y);
      o0.z = f32_to_bf16(u.z); o0.w = f32_to_bf16(u.w);
      o1.x = f32_to_bf16(v.x); o1.y = f32_to_bf16(v.y);
      o1.z = f32_to_bf16(v.z); o1.w = f32_to_bf16(v.w);
    } else {
      o0.x = o0.y = o0.z = o0.w = 0;
      o1.x = o1.y = o1.z = o1.w = 0;
    }
    ushort4* d = (ushort4*)(entb + (long)row * KP + c8);
    d[0] = o0; d[1] = o1;
  } else if (blockIdx.x < GATH_OFF) {
    int g = (blockIdx.x - ENT_BLKS) * 256 + threadIdx.x;   // x8 elems; 2,073,600 total
    float sq = 0.f;
    if (g < 259200) {
      const float4* s = (const float4*)(fcw + (long)g * 8);
      float4 u = s[0], v = s[1];
      sq = u.x*u.x + u.y*u.y + u.z*u.z + u.w*u.w
         + v.x*v.x + v.y*v.y + v.z*v.z + v.w*v.w;
      ushort4 o0, o1;
      o0.x = f32_to_bf16(u.x); o0.y = f32_to_bf16(u.y);
      o0.z = f32_to_bf16(u.z); o0.w = f32_to_bf16(u.w);
      o1.x = f32_to_bf16(v.x); o1.y = f32_to_bf16(v.y);
      o1.z = f32_to_bf16(v.z); o1.w = f32_to_bf16(v.w);
      ushort4* d = (ushort4*)(fcwb + (long)g * 8);
      d[0] = o0; d[1] = o1;
    }
    __shared__ float sbuf[8];
    float tq = blk_reduce(sq, sbuf);
    if (threadIdx.x == 0) atomicAdd(&dacc[67], (double)tq);
  } else {
    int b = blockIdx.x - GATH_OFF;
    int hi = h[b], ri = r[b];
    float s = 0.f, sq = 0.f;
    for (int i = threadIdx.x; i < 400; i += 256) {
      float v = (i < 200) ? ent[(long)hi * DD + i] : rel[(long)ri * DD + (i - 200)];
      x0[b * 400 + i] = v;
      s += v; sq += v * v;
    }
    __shared__ float sbuf[8];
    float ts = blk_reduce(s, sbuf);
    float tq = blk_reduce(sq, sbuf);
    if (threadIdx.x == 0) {
      atomicAdd(&dacc[0], (double)ts);
      atomicAdd(&dacc[1], (double)tq);
    }
  }
}

// K2: bn0 + conv3x3 + conv_b -> yb bf16 [512 x 10368] (pre-bn1); bn1 stats (f32)
__global__ __launch_bounds__(256) void k_conv(const float* __restrict__ x0,
                       const float* __restrict__ convw, const float* __restrict__ convb,
                       const float* __restrict__ g0, const float* __restrict__ b0,
                       unsigned short* __restrict__ yb, double* dacc) {
  __shared__ float xs[400], wsm[288], cbs[32], ssum[32], ssq[32];
  __shared__ float a0s, s0s;
  int b = blockIdx.x, t = threadIdx.x;
  for (int i = t; i < 400; i += 256) xs[i] = x0[b * 400 + i];
  for (int i = t; i < 288; i += 256) wsm[i] = convw[i];
  if (t < 32) cbs[t] = convb[t];
  if (t == 0) {
    double m = dacc[0] / 204800.0;
    double v = dacc[1] / 204800.0 - m * m;
    float a = g0[0] * rsqrtf((float)v + BNEPS);
    a0s = a; s0s = b0[0] - (float)m * a;
  }
  __syncthreads();
  float a0 = a0s, s0 = s0s;
  for (int i = t; i < 400; i += 256) xs[i] = a0 * xs[i] + s0;
  __syncthreads();
  int c = t >> 3, sub = t & 7;
  const float* w = &wsm[c * 9];
  float cb = cbs[c];
  float s = 0.f, sq = 0.f;
  for (int e = sub; e < HW; e += 8) {
    int oh = e / 18, ow = e - oh * 18;
    const float* xp = &xs[oh * 20 + ow];
    float acc = cb
       + xp[0] * w[0] + xp[1] * w[1] + xp[2] * w[2]
       + xp[20] * w[3] + xp[21] * w[4] + xp[22] * w[5]
       + xp[40] * w[6] + xp[41] * w[7] + xp[42] * w[8];
    yb[(long)b * FCIN + c * HW + e] = f32_to_bf16(acc);
    s += acc; sq += acc * acc;
  }
  s += __shfl_xor(s, 1, 64); sq += __shfl_xor(sq, 1, 64);
  s += __shfl_xor(s, 2, 64); sq += __shfl_xor(sq, 2, 64);
  s += __shfl_xor(s, 4, 64); sq += __shfl_xor(sq, 4, 64);
  if (sub == 0) { ssum[c] = s; ssq[c] = sq; }
  __syncthreads();
  if (t < 32) {
    atomicAdd(&dacc[2 + t], (double)ssum[t]);
    atomicAdd(&dacc[34 + t], (double)ssq[t]);
  }
}

// K3: in-place bn1 + relu on yb (bf16); a1/sh1 computed per-block from dacc
__global__ __launch_bounds__(256) void k_prep(unsigned short* __restrict__ yb,
                                              const float* __restrict__ g1,
                                              const float* __restrict__ b1,
                                              const double* __restrict__ dacc) {
  __shared__ float a1s[32], sh1s[32];
  int t = threadIdx.x;
  if (t < 32) {
    double cnt = 512.0 * 324.0;
    double m = dacc[2 + t] / cnt, v = dacc[34 + t] / cnt - m * m;
    float a = g1[t] * rsqrtf((float)v + BNEPS);
    a1s[t] = a; sh1s[t] = b1[t] - (float)m * a;
  }
  __syncthreads();
  int g = blockIdx.x * 256 + t;          // 0..663551 (x8 elems)
  int row = g / 1296;
  int c8 = (g - row * 1296) * 8;
  unsigned short* p = yb + (long)row * FCIN + c8;
  ushort4 v0 = ((ushort4*)p)[0], v1 = ((ushort4*)p)[1];
  unsigned short e[8] = {v0.x, v0.y, v0.z, v0.w, v1.x, v1.y, v1.z, v1.w};
#pragma unroll
  for (int j = 0; j < 8; j++) {
    int c = (c8 + j) / HW;
    float f = a1s[c] * bf16_to_f32(e[j]) + sh1s[c];
    e[j] = f32_to_bf16(fmaxf(f, 0.f));
  }
  v0.x = e[0]; v0.y = e[1]; v0.z = e[2]; v0.w = e[3];
  v1.x = e[4]; v1.y = e[5]; v1.z = e[6]; v1.w = e[7];
  ((ushort4*)p)[0] = v0; ((ushort4*)p)[1] = v1;
}

// K4: FC GEMM via bf16 MFMA. 384 single-wave blocks = 12 kslices x (8 mt x 4 nt).
// Each wave: 64(b) x 64(d) tile over 27 contiguous 32-k chunks (statically
// unrolled 3-buffer pipeline — NO runtime-indexed register arrays!), then writes
// its tile to partial buffer Cp[ks]. No LDS, no atomics.
__global__ __launch_bounds__(64) void k_fc3(const unsigned short* __restrict__ yb,
                                            const unsigned short* __restrict__ fcwb,
                                            float* __restrict__ Cp) {
  int wid = blockIdx.x;             // 384 = 12 ks * 32 tiles
  int ks = wid >> 5, rem = wid & 31;
  int mt = rem >> 2, nt = rem & 3;
  int m0 = mt * 64, n0 = nt * 64;
  int lane = threadIdx.x;
  int quad = lane >> 4, lr = lane & 15;
  long kbeg = (long)ks * 864;       // 27 chunks of 32

  const unsigned short* arow[4];
  const unsigned short* brow[4];
#pragma unroll
  for (int mi = 0; mi < 4; mi++)
    arow[mi] = yb + (long)(m0 + mi * 16 + lr) * FCIN + kbeg + quad * 8;
#pragma unroll
  for (int ni = 0; ni < 4; ni++) {
    int d = n0 + ni * 16 + lr;
    if (d > DD - 1) d = DD - 1;
    brow[ni] = fcwb + (long)d * FCIN + kbeg + quad * 8;
  }

  floatx4 acc[4][4];
#pragma unroll
  for (int i = 0; i < 4; i++)
#pragma unroll
    for (int j = 0; j < 4; j++) acc[i][j] = (floatx4){0.f, 0.f, 0.f, 0.f};

  short8 sA[3][4], sB[3][4];
#pragma unroll
  for (int c = 0; c < 3; c++) {
#pragma unroll
    for (int mi = 0; mi < 4; mi++) sA[c][mi] = *(const short8*)(arow[mi] + c * 32);
#pragma unroll
    for (int ni = 0; ni < 4; ni++) sB[c][ni] = *(const short8*)(brow[ni] + c * 32);
  }
  for (int c3 = 0; c3 < 9; c3++) {
    int cc = c3 * 3;
#pragma unroll
    for (int j = 0; j < 3; j++) {
#pragma unroll
      for (int ni = 0; ni < 4; ni++)
#pragma unroll
        for (int mi = 0; mi < 4; mi++)
          acc[mi][ni] = __builtin_amdgcn_mfma_f32_16x16x32_bf16(sA[j][mi], sB[j][ni], acc[mi][ni], 0, 0, 0);
      int nxt = cc + j + 3;
      if (nxt < 27) {
#pragma unroll
        for (int mi = 0; mi < 4; mi++) sA[j][mi] = *(const short8*)(arow[mi] + nxt * 32);
#pragma unroll
        for (int ni = 0; ni < 4; ni++) sB[j][ni] = *(const short8*)(brow[ni] + nxt * 32);
      }
    }
  }

  float* out = Cp + (long)ks * (NB_B * DD);
#pragma unroll
  for (int ni = 0; ni < 4; ni++) {
    int d = n0 + ni * 16 + lr;
    if (d < DD) {
#pragma unroll
      for (int mi = 0; mi < 4; mi++) {
        int mbase = m0 + mi * 16 + quad * 4;
#pragma unroll
        for (int rg = 0; rg < 4; rg++)
          out[(mbase + rg) * DD + d] = acc[mi][ni][rg];
      }
    }
  }
}

// K4b: reduce 12 partials -> Cfc. 102400 floats = 25600 float4.
__global__ __launch_bounds__(256) void k_fcred(const float* __restrict__ Cp,
                                               float* __restrict__ Cfc) {
  int g = blockIdx.x * 256 + threadIdx.x;   // 0..25599
  float4 s = ((const float4*)Cp)[g];
#pragma unroll
  for (int p = 1; p < 12; p++) {
    float4 v = ((const float4*)(Cp + (long)p * (NB_B * DD)))[g];
    s.x += v.x; s.y += v.y; s.z += v.z; s.w += v.w;
  }
  ((float4*)Cfc)[g] = s;
}

// K5: bn2 stats per feature -> a2/b2c
__global__ void k_bn2stats(const float* __restrict__ Cfc, const float* __restrict__ fcb,
                           const float* __restrict__ g2, const float* __restrict__ b2,
                           float* __restrict__ a2, float* __restrict__ b2c) {
  int d = blockIdx.x, lane = threadIdx.x;  // 64 threads
  float s = 0.f, sq = 0.f;
  for (int b = lane; b < NB_B; b += 64) {
    float v = Cfc[b * DD + d] + fcb[d];
    s += v; sq += v * v;
  }
  for (int o = 32; o > 0; o >>= 1) { s += __shfl_down(s, o, 64); sq += __shfl_down(sq, o, 64); }
  if (lane == 0) {
    float m = s / 512.f, v = sq / 512.f - m * m;
    float a = g2[d] * rsqrtf(v + BNEPS);
    a2[d] = a; b2c[d] = b2[d] - m * a;
  }
}

// K6: x_final row: leaky_relu(bn2(fc)) -> xf f32 + xfb bf16(padded); fused pos-score
__global__ __launch_bounds__(256) void k_xfinal(const float* __restrict__ Cfc,
                         const float* __restrict__ fcb,
                         const float* __restrict__ a2, const float* __restrict__ b2c,
                         const float* __restrict__ ent, const float* __restrict__ bias,
                         const int* __restrict__ pos,
                         float* __restrict__ xf, unsigned short* __restrict__ xfb,
                         double* dacc) {
  __shared__ float xs[224];
  __shared__ float sbuf[8];
  int b = blockIdx.x, t = threadIdx.x;
  if (t < KP) {
    float xv = 0.f;
    if (t < DD) {
      float v = Cfc[b * DD + t] + fcb[t];
      xv = a2[t] * v + b2c[t];
      xv = xv >= 0.f ? xv : 0.01f * xv;
      xf[b * DD + t] = xv;
    }
    xfb[b * KP + t] = f32_to_bf16(xv);
    xs[t] = xv;
  }
  __syncthreads();
  int e = pos[b];
  float s = (t < DD) ? xs[t] * ent[(long)e * DD + t] : 0.f;
  float ts = blk_reduce(s, sbuf);
  if (t == 0) atomicAdd(&dacc[70], (double)(ts + bias[e]));
}

// K7: scores GEMM + fused softplus loss. 512 thr = 8 waves x 64 batch rows = all 512
// rows per block (entb read ONCE grid-wide). 521 blocks x exactly 3 contiguous tiles.
// af register-resident (amdgpu_waves_per_eu(2,2) pins the allocator); cross-tile
// rolling B prefetch so the epilogue hides next-tile load latency.
__global__ __attribute__((amdgpu_flat_work_group_size(512, 512), amdgpu_waves_per_eu(2, 2)))
void k_scores3(const unsigned short* __restrict__ entb,  // [NE_PAD(+64)][KP] bf16
               const unsigned short* __restrict__ xfb,   // [512][KP] bf16
               const float* __restrict__ bias, double* dacc) {
  __shared__ float sbuf[8];
  int t = threadIdx.x;
  int wv = t >> 6, lane = t & 63;
  int quad = lane >> 4, lr = lane & 15;

  // A fragments: 64 batch rows per wave, resident for whole kernel (112 VGPR)
  short8 af[4][7];
#pragma unroll
  for (int mi = 0; mi < 4; mi++) {
    const unsigned short* ap = xfb + (size_t)(wv * 64 + mi * 16 + lr) * KP + quad * 8;
#pragma unroll
    for (int kc = 0; kc < 7; kc++) af[mi][kc] = *(const short8*)(ap + kc * 32);
  }

  int t0 = blockIdx.x * 3;
  const unsigned short* bp[4];
#pragma unroll
  for (int ni = 0; ni < 4; ni++)
    bp[ni] = entb + (size_t)(t0 * 64 + ni * 16 + lr) * KP + quad * 8;

  float sp = 0.f, ss = 0.f;
  short8 bs[2][4];
#pragma unroll
  for (int ni = 0; ni < 4; ni++) bs[0][ni] = *(const short8*)(bp[ni]);
#pragma unroll
  for (int ni = 0; ni < 4; ni++) bs[1][ni] = *(const short8*)(bp[ni] + 32);

#pragma unroll
  for (int tile = 0; tile < 3; tile++) {
    int e0 = (t0 + tile) * 64;
    float b4[4], g4[4];
#pragma unroll
    for (int ni = 0; ni < 4; ni++) {
      int e = e0 + ni * 16 + lr;
      int ec = e < NE ? e : (NE - 1);
      b4[ni] = bias[ec];
      g4[ni] = (e < NE) ? 1.f : 0.f;
    }
    const unsigned short* bpn[4];
#pragma unroll
    for (int ni = 0; ni < 4; ni++) bpn[ni] = bp[ni] + 64 * KP;

    floatx4 acc[4][4];
#pragma unroll
    for (int i = 0; i < 4; i++)
#pragma unroll
      for (int j = 0; j < 4; j++) acc[i][j] = (floatx4){0.f, 0.f, 0.f, 0.f};

#pragma unroll
    for (int kc = 0; kc < 7; kc++) {
      int s = kc & 1;
#pragma unroll
      for (int ni = 0; ni < 4; ni++)
#pragma unroll
        for (int mi = 0; mi < 4; mi++)
          acc[mi][ni] = __builtin_amdgcn_mfma_f32_16x16x32_bf16(af[mi][kc], bs[s][ni], acc[mi][ni], 0, 0, 0);
      if (kc < 5) {
        // prefetch this tile's chunk kc+2 into the just-freed buffer
#pragma unroll
        for (int ni = 0; ni < 4; ni++) bs[s][ni] = *(const short8*)(bp[ni] + (kc + 2) * 32);
      } else {
        // rolling prefetch of NEXT tile: kc=5 -> chunk1 (used at next kc=1),
        // kc=6 -> chunk0 (used at next kc=0); epilogue below hides the latency.
        int nc = (kc == 5) ? 1 : 0;
#pragma unroll
        for (int ni = 0; ni < 4; ni++) bs[s][ni] = *(const short8*)(bpn[ni] + nc * 32);
      }
    }

    // epilogue: row(batch) = wv*64 + mi*16 + quad*4 + rg, col(entity) = e0 + ni*16 + lr
#pragma unroll
    for (int ni = 0; ni < 4; ni++) {
      float gl = g4[ni] * 0.6931471805599453f;  // gate * ln2
#pragma unroll
      for (int mi = 0; mi < 4; mi++) {
#pragma unroll
        for (int rg = 0; rg < 4; rg++) {
          float s1 = acc[mi][ni][rg] + b4[ni];
          float m = fmaxf(s1, 0.f);
          float ex = __builtin_amdgcn_exp2f(__builtin_fabsf(s1) * -1.4426950408889634f);
          float lg = __builtin_amdgcn_logf(1.f + ex);  // log2(1+ex)
          sp = fmaf(g4[ni], m, sp);
          sp = fmaf(gl, lg, sp);
          ss = fmaf(g4[ni], s1, ss);
        }
      }
    }
#pragma unroll
    for (int ni = 0; ni < 4; ni++) bp[ni] = bpn[ni];
  }

  float tsp = blk_reduce(sp, sbuf);
  float tss = blk_reduce(ss, sbuf);
  if (t == 0) {
    atomicAdd(&dacc[68], (double)tsp);
    atomicAdd(&dacc[69], (double)tss);
  }
}

// K8: final scalar (64 threads; also does conv_w L2 reduce)
__global__ void k_final(const float* __restrict__ convw, const double* dacc, float* out) {
  int t = threadIdx.x;
  float sq = 0.f;
  for (int i = t; i < 288; i += 64) { float w = convw[i]; sq += w * w; }
  for (int o = 32; o > 0; o >>= 1) sq += __shfl_down(sq, o, 64);
  if (t == 0) {
    double SP = dacc[68], S2 = dacc[69], S3 = dacc[70];
    double xy = S2 / (double)NE + 0.9 * S3;
    double kg = (SP - xy) / ((double)NB_B * (double)NE);
    double l2 = dacc[1] / 204800.0 + (double)sq / 576.0 + dacc[67] / 400.0;
    out[0] = (float)(kg + 1e-5 * l2);
  }
}

extern "C" void kernel_launch(void* const* d_in, const int* in_sizes, int n_in,
                              void* d_out, int out_size, void* d_ws, size_t ws_size,
                              hipStream_t stream) {
  const float* ent   = (const float*)d_in[0];
  const float* rel   = (const float*)d_in[1];
  const float* convw = (const float*)d_in[2];
  const float* convb = (const float*)d_in[3];
  const float* fcw   = (const float*)d_in[4];
  const float* fcb   = (const float*)d_in[5];
  const float* bias  = (const float*)d_in[6];
  const float* g0    = (const float*)d_in[7];
  const float* b0    = (const float*)d_in[8];
  const float* g1    = (const float*)d_in[9];
  const float* b1    = (const float*)d_in[10];
  const float* g2    = (const float*)d_in[11];
  const float* b2    = (const float*)d_in[12];
  const int*   h     = (const int*)d_in[13];
  const int*   r     = (const int*)d_in[14];
  const int*   pos   = (const int*)d_in[15];

  char* ws = (char*)d_ws;
  double* dacc = (double*)(ws + 0);                        // 8 KB
  float* a2  = (float*)(ws + 16384 + 256);                 // 200
  float* b2c = (float*)(ws + 16384 + 1056);                // 200
  float* x0  = (float*)(ws + 32768);                       // 512*400 f32      (819200 B)
  float* Cfc = (float*)(ws + 851968);                      // 512*200 f32      (409600 B)
  float* xf  = (float*)(ws + 1261568);                     // 512*200 f32      (409600 B)
  unsigned short* yb   = (unsigned short*)(ws + 1671168);  // 512*10368 bf16   (10616832 B)
  unsigned short* fcwb = (unsigned short*)(ws + 12288000); // 200*10368 bf16   (4147200 B)
  unsigned short* xfb  = (unsigned short*)(ws + 16435200); // 512*224 bf16     (229376 B)
  unsigned short* entb = (unsigned short*)(ws + 16664576); // (100032+64)*224 bf16 (44843008 B)
  float* Cp = (float*)(ws + 61507584);                     // 12*512*200 f32   (4915200 B) -> 66.4MB

  hipMemsetAsync(dacc, 0, 8192, stream);

  k_cvt<<<GATH_OFF + 512, 256, 0, stream>>>(ent, entb, fcw, fcwb, rel, h, r, x0, dacc);
  k_conv<<<512, 256, 0, stream>>>(x0, convw, convb, g0, b0, yb, dacc);
  k_prep<<<2592, 256, 0, stream>>>(yb, g1, b1, dacc);
  k_fc3<<<384, 64, 0, stream>>>(yb, fcwb, Cp);
  k_fcred<<<100, 256, 0, stream>>>(Cp, Cfc);
  k_bn2stats<<<200, 64, 0, stream>>>(Cfc, fcb, g2, b2, a2, b2c);
  k_xfinal<<<512, 256, 0, stream>>>(Cfc, fcb, a2, b2c, ent, bias, pos, xf, xfb, dacc);
  k_scores3<<<521, 512, 0, stream>>>(entb, xfb, bias, dacc);
  k_final<<<1, 64, 0, stream>>>(convw, dacc, (float*)d_out);
}

// Round 9
// 323.875 us; speedup vs baseline: 2.0663x; 1.1480x over previous
//
#include <hip/hip_runtime.h>
#include <math.h>

#define NB_B 512
#define NE 100000
#define NE_PAD 100032   // padded to multiple of 64 (zero rows 100000..100031)
#define DD 200
#define CC 32
#define FCIN 10368   // 32*18*18
#define HW 324       // 18*18
#define BNEPS 1e-5f
#define KP 224       // scores K padded to multiple of 32 for MFMA

#define ENT_BLKS 10941   // 100032*28/256 exactly
#define FCW_BLKS 1013
#define GATH_OFF (ENT_BLKS + FCW_BLKS)   // 11954

typedef __attribute__((ext_vector_type(8))) short short8;   // 8 bf16 = 4 VGPRs
typedef __attribute__((ext_vector_type(4))) float floatx4;  // MFMA acc

// dacc (double) slots:
// 0: bn0 sum, 1: bn0 sumsq (also l2 for h_e+r_e)
// 2..33: bn1 per-channel sum, 34..65: bn1 per-channel sumsq
// 67: fc_w sumsq, 68: softplus sum (incl. pad constant), 69: scores sum, 70: pos-scores sum

static __device__ __forceinline__ float blk_reduce(float v, volatile float* sbuf) {
  for (int o = 32; o > 0; o >>= 1) v += __shfl_down(v, o, 64);
  int lane = threadIdx.x & 63, wid = threadIdx.x >> 6;
  if (lane == 0) sbuf[wid] = v;
  __syncthreads();
  float r = 0.f;
  int nw = (blockDim.x + 63) >> 6;
  if ((int)threadIdx.x < nw) r = sbuf[threadIdx.x];
  if (threadIdx.x < 64) {
    for (int o = 32; o > 0; o >>= 1) r += __shfl_down(r, o, 64);
  }
  __syncthreads();
  return r;  // valid on thread 0
}

static __device__ __forceinline__ unsigned short f32_to_bf16(float f) {
  unsigned int u = __float_as_uint(f);
  u += 0x7fffu + ((u >> 16) & 1u);  // round-to-nearest-even
  return (unsigned short)(u >> 16);
}
static __device__ __forceinline__ float bf16_to_f32(unsigned short b) {
  return __uint_as_float(((unsigned int)b) << 16);
}

// K1: fused prep. Blocks [0,ENT_BLKS): entity_w f32 -> bf16, rows padded to NE_PAD
// (zero rows >= NE), cols padded 200->224. Blocks [ENT_BLKS,GATH_OFF): fc_w -> bf16
// + sumsq. Blocks [GATH_OFF, +512): gather h/r -> x0, bn0 stats.
__global__ __launch_bounds__(256) void k_cvt(const float* __restrict__ ent,
                                             unsigned short* __restrict__ entb,
                                             const float* __restrict__ fcw,
                                             unsigned short* __restrict__ fcwb,
                                             const float* __restrict__ rel,
                                             const int* __restrict__ h,
                                             const int* __restrict__ r,
                                             float* __restrict__ x0,
                                             double* dacc) {
  if (blockIdx.x < ENT_BLKS) {
    int g = blockIdx.x * 256 + threadIdx.x;   // 0 .. 2,800,895  (100032*28)
    int row = g / 28;
    int c8 = (g - row * 28) * 8;
    ushort4 o0, o1;
    if (c8 < 200 && row < NE) {
      const float4* s = (const float4*)(ent + (long)row * DD + c8);
      float4 u = s[0], v = s[1];
      o0.x = f32_to_bf16(u.x); o0.y = f32_to_bf16(u.y);
      o0.z = f32_to_bf16(u.z); o0.w = f32_to_bf16(u.w);
      o1.x = f32_to_bf16(v.x); o1.y = f32_to_bf16(v.y);
      o1.z = f32_to_bf16(v.z); o1.w = f32_to_bf16(v.w);
    } else {
      o0.x = o0.y = o0.z = o0.w = 0;
      o1.x = o1.y = o1.z = o1.w = 0;
    }
    ushort4* d = (ushort4*)(entb + (long)row * KP + c8);
    d[0] = o0; d[1] = o1;
  } else if (blockIdx.x < GATH_OFF) {
    int g = (blockIdx.x - ENT_BLKS) * 256 + threadIdx.x;   // x8 elems; 2,073,600 total
    float sq = 0.f;
    if (g < 259200) {
      const float4* s = (const float4*)(fcw + (long)g * 8);
      float4 u = s[0], v = s[1];
      sq = u.x*u.x + u.y*u.y + u.z*u.z + u.w*u.w
         + v.x*v.x + v.y*v.y + v.z*v.z + v.w*v.w;
      ushort4 o0, o1;
      o0.x = f32_to_bf16(u.x); o0.y = f32_to_bf16(u.y);
      o0.z = f32_to_bf16(u.z); o0.w = f32_to_bf16(u.w);
      o1.x = f32_to_bf16(v.x); o1.y = f32_to_bf16(v.y);
      o1.z = f32_to_bf16(v.z); o1.w = f32_to_bf16(v.w);
      ushort4* d = (ushort4*)(fcwb + (long)g * 8);
      d[0] = o0; d[1] = o1;
    }
    __shared__ float sbuf[8];
    float tq = blk_reduce(sq, sbuf);
    if (threadIdx.x == 0) atomicAdd(&dacc[67], (double)tq);
  } else {
    int b = blockIdx.x - GATH_OFF;
    int hi = h[b], ri = r[b];
    float s = 0.f, sq = 0.f;
    for (int i = threadIdx.x; i < 400; i += 256) {
      float v = (i < 200) ? ent[(long)hi * DD + i] : rel[(long)ri * DD + (i - 200)];
      x0[b * 400 + i] = v;
      s += v; sq += v * v;
    }
    __shared__ float sbuf[8];
    float ts = blk_reduce(s, sbuf);
    float tq = blk_reduce(sq, sbuf);
    if (threadIdx.x == 0) {
      atomicAdd(&dacc[0], (double)ts);
      atomicAdd(&dacc[1], (double)tq);
    }
  }
}

// K2: bn0 + conv3x3 + conv_b -> yb bf16 [512 x 10368] (pre-bn1); bn1 stats (f32)
__global__ __launch_bounds__(256) void k_conv(const float* __restrict__ x0,
                       const float* __restrict__ convw, const float* __restrict__ convb,
                       const float* __restrict__ g0, const float* __restrict__ b0,
                       unsigned short* __restrict__ yb, double* dacc) {
  __shared__ float xs[400], wsm[288], cbs[32], ssum[32], ssq[32];
  __shared__ float a0s, s0s;
  int b = blockIdx.x, t = threadIdx.x;
  for (int i = t; i < 400; i += 256) xs[i] = x0[b * 400 + i];
  for (int i = t; i < 288; i += 256) wsm[i] = convw[i];
  if (t < 32) cbs[t] = convb[t];
  if (t == 0) {
    double m = dacc[0] / 204800.0;
    double v = dacc[1] / 204800.0 - m * m;
    float a = g0[0] * rsqrtf((float)v + BNEPS);
    a0s = a; s0s = b0[0] - (float)m * a;
  }
  __syncthreads();
  float a0 = a0s, s0 = s0s;
  for (int i = t; i < 400; i += 256) xs[i] = a0 * xs[i] + s0;
  __syncthreads();
  int c = t >> 3, sub = t & 7;
  const float* w = &wsm[c * 9];
  float cb = cbs[c];
  float s = 0.f, sq = 0.f;
  for (int e = sub; e < HW; e += 8) {
    int oh = e / 18, ow = e - oh * 18;
    const float* xp = &xs[oh * 20 + ow];
    float acc = cb
       + xp[0] * w[0] + xp[1] * w[1] + xp[2] * w[2]
       + xp[20] * w[3] + xp[21] * w[4] + xp[22] * w[5]
       + xp[40] * w[6] + xp[41] * w[7] + xp[42] * w[8];
    yb[(long)b * FCIN + c * HW + e] = f32_to_bf16(acc);
    s += acc; sq += acc * acc;
  }
  s += __shfl_xor(s, 1, 64); sq += __shfl_xor(sq, 1, 64);
  s += __shfl_xor(s, 2, 64); sq += __shfl_xor(sq, 2, 64);
  s += __shfl_xor(s, 4, 64); sq += __shfl_xor(sq, 4, 64);
  if (sub == 0) { ssum[c] = s; ssq[c] = sq; }
  __syncthreads();
  if (t < 32) {
    atomicAdd(&dacc[2 + t], (double)ssum[t]);
    atomicAdd(&dacc[34 + t], (double)ssq[t]);
  }
}

// K3: in-place bn1 + relu on yb (bf16); a1/sh1 computed per-block from dacc
__global__ __launch_bounds__(256) void k_prep(unsigned short* __restrict__ yb,
                                              const float* __restrict__ g1,
                                              const float* __restrict__ b1,
                                              const double* __restrict__ dacc) {
  __shared__ float a1s[32], sh1s[32];
  int t = threadIdx.x;
  if (t < 32) {
    double cnt = 512.0 * 324.0;
    double m = dacc[2 + t] / cnt, v = dacc[34 + t] / cnt - m * m;
    float a = g1[t] * rsqrtf((float)v + BNEPS);
    a1s[t] = a; sh1s[t] = b1[t] - (float)m * a;
  }
  __syncthreads();
  int g = blockIdx.x * 256 + t;          // 0..663551 (x8 elems)
  int row = g / 1296;
  int c8 = (g - row * 1296) * 8;
  unsigned short* p = yb + (long)row * FCIN + c8;
  ushort4 v0 = ((ushort4*)p)[0], v1 = ((ushort4*)p)[1];
  unsigned short e[8] = {v0.x, v0.y, v0.z, v0.w, v1.x, v1.y, v1.z, v1.w};
#pragma unroll
  for (int j = 0; j < 8; j++) {
    int c = (c8 + j) / HW;
    float f = a1s[c] * bf16_to_f32(e[j]) + sh1s[c];
    e[j] = f32_to_bf16(fmaxf(f, 0.f));
  }
  v0.x = e[0]; v0.y = e[1]; v0.z = e[2]; v0.w = e[3];
  v1.x = e[4]; v1.y = e[5]; v1.z = e[6]; v1.w = e[7];
  ((ushort4*)p)[0] = v0; ((ushort4*)p)[1] = v1;
}

// K4: FC GEMM via bf16 MFMA. 384 single-wave blocks = 12 kslices x (8 mt x 4 nt).
// Statically-unrolled 3-buffer pipeline (no runtime-indexed register arrays);
// each wave writes its 64x64 tile to partial buffer Cp[ks]. No LDS, no atomics.
__global__ __launch_bounds__(64) void k_fc3(const unsigned short* __restrict__ yb,
                                            const unsigned short* __restrict__ fcwb,
                                            float* __restrict__ Cp) {
  int wid = blockIdx.x;             // 384 = 12 ks * 32 tiles
  int ks = wid >> 5, rem = wid & 31;
  int mt = rem >> 2, nt = rem & 3;
  int m0 = mt * 64, n0 = nt * 64;
  int lane = threadIdx.x;
  int quad = lane >> 4, lr = lane & 15;
  long kbeg = (long)ks * 864;       // 27 chunks of 32

  const unsigned short* arow[4];
  const unsigned short* brow[4];
#pragma unroll
  for (int mi = 0; mi < 4; mi++)
    arow[mi] = yb + (long)(m0 + mi * 16 + lr) * FCIN + kbeg + quad * 8;
#pragma unroll
  for (int ni = 0; ni < 4; ni++) {
    int d = n0 + ni * 16 + lr;
    if (d > DD - 1) d = DD - 1;
    brow[ni] = fcwb + (long)d * FCIN + kbeg + quad * 8;
  }

  floatx4 acc[4][4];
#pragma unroll
  for (int i = 0; i < 4; i++)
#pragma unroll
    for (int j = 0; j < 4; j++) acc[i][j] = (floatx4){0.f, 0.f, 0.f, 0.f};

  short8 sA[3][4], sB[3][4];
#pragma unroll
  for (int c = 0; c < 3; c++) {
#pragma unroll
    for (int mi = 0; mi < 4; mi++) sA[c][mi] = *(const short8*)(arow[mi] + c * 32);
#pragma unroll
    for (int ni = 0; ni < 4; ni++) sB[c][ni] = *(const short8*)(brow[ni] + c * 32);
  }
  for (int c3 = 0; c3 < 9; c3++) {
    int cc = c3 * 3;
#pragma unroll
    for (int j = 0; j < 3; j++) {
#pragma unroll
      for (int ni = 0; ni < 4; ni++)
#pragma unroll
        for (int mi = 0; mi < 4; mi++)
          acc[mi][ni] = __builtin_amdgcn_mfma_f32_16x16x32_bf16(sA[j][mi], sB[j][ni], acc[mi][ni], 0, 0, 0);
      int nxt = cc + j + 3;
      if (nxt < 27) {
#pragma unroll
        for (int mi = 0; mi < 4; mi++) sA[j][mi] = *(const short8*)(arow[mi] + nxt * 32);
#pragma unroll
        for (int ni = 0; ni < 4; ni++) sB[j][ni] = *(const short8*)(brow[ni] + nxt * 32);
      }
    }
  }

  float* out = Cp + (long)ks * (NB_B * DD);
#pragma unroll
  for (int ni = 0; ni < 4; ni++) {
    int d = n0 + ni * 16 + lr;
    if (d < DD) {
#pragma unroll
      for (int mi = 0; mi < 4; mi++) {
        int mbase = m0 + mi * 16 + quad * 4;
#pragma unroll
        for (int rg = 0; rg < 4; rg++)
          out[(mbase + rg) * DD + d] = acc[mi][ni][rg];
      }
    }
  }
}

// K4b: reduce 12 partials -> Cfc. 102400 floats = 25600 float4.
__global__ __launch_bounds__(256) void k_fcred(const float* __restrict__ Cp,
                                               float* __restrict__ Cfc) {
  int g = blockIdx.x * 256 + threadIdx.x;   // 0..25599
  float4 s = ((const float4*)Cp)[g];
#pragma unroll
  for (int p = 1; p < 12; p++) {
    float4 v = ((const float4*)(Cp + (long)p * (NB_B * DD)))[g];
    s.x += v.x; s.y += v.y; s.z += v.z; s.w += v.w;
  }
  ((float4*)Cfc)[g] = s;
}

// K5: bn2 stats per feature -> a2/b2c
__global__ void k_bn2stats(const float* __restrict__ Cfc, const float* __restrict__ fcb,
                           const float* __restrict__ g2, const float* __restrict__ b2,
                           float* __restrict__ a2, float* __restrict__ b2c) {
  int d = blockIdx.x, lane = threadIdx.x;  // 64 threads
  float s = 0.f, sq = 0.f;
  for (int b = lane; b < NB_B; b += 64) {
    float v = Cfc[b * DD + d] + fcb[d];
    s += v; sq += v * v;
  }
  for (int o = 32; o > 0; o >>= 1) { s += __shfl_down(s, o, 64); sq += __shfl_down(sq, o, 64); }
  if (lane == 0) {
    float m = s / 512.f, v = sq / 512.f - m * m;
    float a = g2[d] * rsqrtf(v + BNEPS);
    a2[d] = a; b2c[d] = b2[d] - m * a;
  }
}

// K6: x_final row: leaky_relu(bn2(fc)) -> xf f32 + xfb bf16(padded); fused pos-score
__global__ __launch_bounds__(256) void k_xfinal(const float* __restrict__ Cfc,
                         const float* __restrict__ fcb,
                         const float* __restrict__ a2, const float* __restrict__ b2c,
                         const float* __restrict__ ent, const float* __restrict__ bias,
                         const int* __restrict__ pos,
                         float* __restrict__ xf, unsigned short* __restrict__ xfb,
                         double* dacc) {
  __shared__ float xs[224];
  __shared__ float sbuf[8];
  int b = blockIdx.x, t = threadIdx.x;
  if (t < KP) {
    float xv = 0.f;
    if (t < DD) {
      float v = Cfc[b * DD + t] + fcb[t];
      xv = a2[t] * v + b2c[t];
      xv = xv >= 0.f ? xv : 0.01f * xv;
      xf[b * DD + t] = xv;
    }
    xfb[b * KP + t] = f32_to_bf16(xv);
    xs[t] = xv;
  }
  __syncthreads();
  int e = pos[b];
  float s = (t < DD) ? xs[t] * ent[(long)e * DD + t] : 0.f;
  float ts = blk_reduce(s, sbuf);
  if (t == 0) atomicAdd(&dacc[70], (double)(ts + bias[e]));
}

// K7: scores GEMM + fused softplus loss. R4-proven structure: 512 thr = 8 waves,
// wave w owns batch rows [w*64, w*64+64); per-tile B double-buffer prefetch.
// 521 blocks x 3 contiguous tiles (1563 = 521*3). Pad entities (>=NE) have zero
// embedding and zero bias -> s=0 -> softplus contributes exactly ln2 each,
// subtracted as a constant in k_final. No register-residency pin (R8's spill).
__global__ __launch_bounds__(512) void k_scores4(
    const unsigned short* __restrict__ entb,  // [NE_PAD][KP] bf16 bits
    const unsigned short* __restrict__ xfb,   // [512][KP] bf16 bits
    const float* __restrict__ bias, double* dacc) {
  __shared__ float sbuf[8];
  int t = threadIdx.x;
  int wv = t >> 6, lane = t & 63;
  int quad = lane >> 4, lr = lane & 15;

  short8 af[4][7];
#pragma unroll
  for (int mi = 0; mi < 4; mi++) {
    const unsigned short* ap = xfb + (size_t)(wv * 64 + mi * 16 + lr) * KP + quad * 8;
#pragma unroll
    for (int kc = 0; kc < 7; kc++) af[mi][kc] = *(const short8*)(ap + kc * 32);
  }

  float sp = 0.f, ss = 0.f;
  int t0 = blockIdx.x * 3;
#pragma unroll 1
  for (int tile = t0; tile < t0 + 3; tile++) {
    int e0 = tile * 64;
    const unsigned short* bp[4];
    float b4[4];
#pragma unroll
    for (int ni = 0; ni < 4; ni++) {
      int e = e0 + ni * 16 + lr;
      int ec = e < NE ? e : (NE - 1);
      bp[ni] = entb + (size_t)e * KP + quad * 8;   // pad rows are zeroed
      float bv = bias[ec];
      b4[ni] = (e < NE) ? bv : 0.f;
    }
    floatx4 acc[4][4];
#pragma unroll
    for (int i = 0; i < 4; i++)
#pragma unroll
      for (int j = 0; j < 4; j++) acc[i][j] = (floatx4){0.f, 0.f, 0.f, 0.f};

    short8 bs[2][4];
#pragma unroll
    for (int ni = 0; ni < 4; ni++) bs[0][ni] = *(const short8*)(bp[ni]);
#pragma unroll
    for (int ni = 0; ni < 4; ni++) bs[1][ni] = *(const short8*)(bp[ni] + 32);
#pragma unroll
    for (int kc = 0; kc < 7; kc++) {
      int s = kc & 1;   // compile-time after full unroll
#pragma unroll
      for (int ni = 0; ni < 4; ni++)
#pragma unroll
        for (int mi = 0; mi < 4; mi++)
          acc[mi][ni] = __builtin_amdgcn_mfma_f32_16x16x32_bf16(af[mi][kc], bs[s][ni], acc[mi][ni], 0, 0, 0);
      if (kc + 2 < 7) {
#pragma unroll
        for (int ni = 0; ni < 4; ni++) bs[s][ni] = *(const short8*)(bp[ni] + (kc + 2) * 32);
      }
    }
    // epilogue in log2 domain: softplus(s) = ln2*(max(m1,0)+log2(1+2^-|m1|)), m1 = s*log2e
#pragma unroll
    for (int ni = 0; ni < 4; ni++) {
#pragma unroll
      for (int mi = 0; mi < 4; mi++) {
#pragma unroll
        for (int rg = 0; rg < 4; rg++) {
          float s1 = acc[mi][ni][rg] + b4[ni];
          ss += s1;
          float m1 = s1 * 1.4426950408889634f;
          float e2 = __builtin_amdgcn_exp2f(-__builtin_fabsf(m1));
          float lg = __builtin_amdgcn_logf(1.f + e2);   // log2(1+e2)
          sp += fmaxf(m1, 0.f) + lg;
        }
      }
    }
  }
  sp *= 0.6931471805599453f;  // ln2
  float tsp = blk_reduce(sp, sbuf);
  float tss = blk_reduce(ss, sbuf);
  if (t == 0) {
    atomicAdd(&dacc[68], (double)tsp);
    atomicAdd(&dacc[69], (double)tss);
  }
}

// K8: final scalar (64 threads; also does conv_w L2 reduce).
// Subtract pad softplus constant: 512 rows x 32 pad entities x ln2.
__global__ void k_final(const float* __restrict__ convw, const double* dacc, float* out) {
  int t = threadIdx.x;
  float sq = 0.f;
  for (int i = t; i < 288; i += 64) { float w = convw[i]; sq += w * w; }
  for (int o = 32; o > 0; o >>= 1) sq += __shfl_down(sq, o, 64);
  if (t == 0) {
    double SP = dacc[68] - 16384.0 * 0.6931471805599453;
    double S2 = dacc[69], S3 = dacc[70];
    double xy = S2 / (double)NE + 0.9 * S3;
    double kg = (SP - xy) / ((double)NB_B * (double)NE);
    double l2 = dacc[1] / 204800.0 + (double)sq / 576.0 + dacc[67] / 400.0;
    out[0] = (float)(kg + 1e-5 * l2);
  }
}

extern "C" void kernel_launch(void* const* d_in, const int* in_sizes, int n_in,
                              void* d_out, int out_size, void* d_ws, size_t ws_size,
                              hipStream_t stream) {
  const float* ent   = (const float*)d_in[0];
  const float* rel   = (const float*)d_in[1];
  const float* convw = (const float*)d_in[2];
  const float* convb = (const float*)d_in[3];
  const float* fcw   = (const float*)d_in[4];
  const float* fcb   = (const float*)d_in[5];
  const float* bias  = (const float*)d_in[6];
  const float* g0    = (const float*)d_in[7];
  const float* b0    = (const float*)d_in[8];
  const float* g1    = (const float*)d_in[9];
  const float* b1    = (const float*)d_in[10];
  const float* g2    = (const float*)d_in[11];
  const float* b2    = (const float*)d_in[12];
  const int*   h     = (const int*)d_in[13];
  const int*   r     = (const int*)d_in[14];
  const int*   pos   = (const int*)d_in[15];

  char* ws = (char*)d_ws;
  double* dacc = (double*)(ws + 0);                        // 8 KB
  float* a2  = (float*)(ws + 16384 + 256);                 // 200
  float* b2c = (float*)(ws + 16384 + 1056);                // 200
  float* x0  = (float*)(ws + 32768);                       // 512*400 f32      (819200 B)
  float* Cfc = (float*)(ws + 851968);                      // 512*200 f32      (409600 B)
  float* xf  = (float*)(ws + 1261568);                     // 512*200 f32      (409600 B)
  unsigned short* yb   = (unsigned short*)(ws + 1671168);  // 512*10368 bf16   (10616832 B)
  unsigned short* fcwb = (unsigned short*)(ws + 12288000); // 200*10368 bf16   (4147200 B)
  unsigned short* xfb  = (unsigned short*)(ws + 16435200); // 512*224 bf16     (229376 B)
  unsigned short* entb = (unsigned short*)(ws + 16664576); // NE_PAD*224 bf16  (44814336 B)
  float* Cp = (float*)(ws + 61507584);                     // 12*512*200 f32   (4915200 B) -> 66.4MB

  hipMemsetAsync(dacc, 0, 8192, stream);

  k_cvt<<<GATH_OFF + 512, 256, 0, stream>>>(ent, entb, fcw, fcwb, rel, h, r, x0, dacc);
  k_conv<<<512, 256, 0, stream>>>(x0, convw, convb, g0, b0, yb, dacc);
  k_prep<<<2592, 256, 0, stream>>>(yb, g1, b1, dacc);
  k_fc3<<<384, 64, 0, stream>>>(yb, fcwb, Cp);
  k_fcred<<<100, 256, 0, stream>>>(Cp, Cfc);
  k_bn2stats<<<200, 64, 0, stream>>>(Cfc, fcb, g2, b2, a2, b2c);
  k_xfinal<<<512, 256, 0, stream>>>(Cfc, fcb, a2, b2c, ent, bias, pos, xf, xfb, dacc);
  k_scores4<<<521, 512, 0, stream>>>(entb, xfb, bias, dacc);
  k_final<<<1, 64, 0, stream>>>(convw, dacc, (float*)d_out);
}